// Round 11
// baseline (430.875 us; speedup 1.0000x reference)
//
#include <hip/hip_runtime.h>
#include <hip/hip_bf16.h>

// GCN 2-layer forward on MI355X.
// Round-20 changes (aggs declared closed: 3 distinct issue-side attacks —
// unroll-8, col-pipeline, octet-split — all flat; agg1 FETCH 90MB ~= 0.88x
// compulsory per-XCD table pull -> irreducible. Last unverified slack is
// the CSR build, which did 4 edge passes + a 19MB tmp round-trip):
//  - direct-scatter build: bhist_k = wprep + per-NODE histogram (1.6M
//    global atomics into ncnt); rp_k = per-bucket block: L2-hot prefix of
//    ncnt + LDS scan -> rpc/dis/curp(=row_ptr); scat_k = 1 edge/thread,
//    col[atomicAdd(&curp[d],1)] = s. tmp/gbc/gcur deleted; 3 edge passes.
//    Neighbor order per node is nondeterministic (sum-order noise << fp8
//    tolerance).
// Aggs/GEMMs untouched (R19 octet form, verified passing): quad-owns-node,
// octet-split gathers, col software-pipeline, sentinel cndmask, pre-scaled
// fp8 features, direct-from-global MFMA A-loads.

typedef unsigned short ushortT;
typedef unsigned char ucharT;
typedef __attribute__((ext_vector_type(8))) short short8v;        // 8 bf16 (4 VGPR)
typedef __attribute__((ext_vector_type(4))) float float4v;        // MFMA C/D
typedef __attribute__((ext_vector_type(2))) float float2v;
typedef __attribute__((ext_vector_type(8))) unsigned short ushort8v;

__device__ __forceinline__ float bf2f(ushortT u) {
  union { unsigned int i; float f; } x;
  x.i = ((unsigned int)u) << 16;
  return x.f;
}

__device__ __forceinline__ ushortT f2bf(float f) {
  __hip_bfloat16 h = __float2bfloat16(f);  // RNE
  return *(ushortT*)&h;
}

__device__ __forceinline__ ucharT f2fp8(float f) {
  unsigned int w = __builtin_amdgcn_cvt_pk_fp8_f32(f, f, 0, false);
  return (ucharT)(w & 0xff);
}

// wave-uniform dtype probe: interpret x's first 64 halfwords as bf16 and
// check sanity. Every wave reads the same hot 128B line. Deterministic.
__device__ __forceinline__ bool probe_isbf(const void* xv) {
  const ushortT* xr = (const ushortT*)xv;
  const int lane = threadIdx.x & 63;
  float v = bf2f(xr[lane]);
  bool sane = isfinite(v) && fabsf(v) < 1e4f;
  return __ballot(sane) == ~0ull;
}

// ---------------- bhist: wprep + per-node degree histogram ----------------
// 1 edge/thread; first 96 blocks also transpose W1/W2.
__global__ __launch_bounds__(256) void bhist_k(const int* __restrict__ dst, int E,
                                               const void* __restrict__ W1v,
                                               const void* __restrict__ W2v,
                                               const void* __restrict__ xv,
                                               ushortT* __restrict__ Wt1,
                                               ushortT* __restrict__ Wt2,
                                               int* __restrict__ ncnt) {
  const int gi = blockIdx.x * 256 + threadIdx.x;
  if (gi < 24576) {
    const bool isbf = probe_isbf(xv);
    if (gi < 16384) {
      int nn = gi & 127, k = gi >> 7;   // read W1[k][nn] coalesced in nn
      ushortT v = isbf ? ((const ushortT*)W1v)[k * 128 + nn]
                       : f2bf(((const float*)W1v)[k * 128 + nn]);
      Wt1[nn * 128 + k] = v;
    } else {
      int j = gi - 16384;
      int nn = j & 63, k = j >> 6;      // read W2[k][nn] coalesced in nn
      ushortT v = isbf ? ((const ushortT*)W2v)[k * 64 + nn]
                       : f2bf(((const float*)W2v)[k * 64 + nn]);
      Wt2[nn * 128 + k] = v;
    }
  }
  if (gi < E) atomicAdd(&ncnt[dst[gi]], 1);
}

// ---------------- rp: per-bucket row_ptr/dis/cursor from ncnt ----------------
// block b: e0 = sum ncnt[0..256b) (L2-hot 400KB), LDS scan of own 256.
__global__ __launch_bounds__(256) void rp_k(const int* __restrict__ ncnt, int n,
                                            int2* __restrict__ rpc,
                                            float* __restrict__ dis,
                                            int* __restrict__ curp) {
  __shared__ int red[256];
  __shared__ int sc[256];
  const int b = blockIdx.x;
  const int tid = threadIdx.x;
  const int node = (b << 8) + tid;
  // e0 = sum of all previous buckets' degrees
  int part = 0;
  for (int i = tid; i < (b << 8); i += 256) part += ncnt[i];
  red[tid] = part;
  __syncthreads();
  for (int off = 128; off > 0; off >>= 1) {
    if (tid < off) red[tid] += red[tid + off];
    __syncthreads();
  }
  const int e0 = red[0];
  // LDS inclusive scan of this bucket's 256 degrees
  const int v = (node < n) ? ncnt[node] : 0;
  int run = v;
  sc[tid] = run;
  __syncthreads();
  for (int off = 1; off < 256; off <<= 1) {
    int t = (tid >= off) ? sc[tid - off] : 0;
    __syncthreads();
    run += t;
    sc[tid] = run;
    __syncthreads();
  }
  const int excl = run - v;
  if (node < n) {
    const int rowp = e0 + excl;
    rpc[node] = make_int2(rowp, v);
    dis[node] = rsqrtf((float)(v + 1));
    curp[node] = rowp;
  }
}

// ---------------- scat: direct CSR scatter (1 edge/thread) ----------------
__global__ __launch_bounds__(256) void scat_k(const int* __restrict__ srcv,
                                              const int* __restrict__ dstv, int E,
                                              int* __restrict__ curp,
                                              int* __restrict__ col) {
  const int i = blockIdx.x * 256 + threadIdx.x;
  if (i >= E) return;
  const int d = dstv[i];
  const int s = srcv[i];
  const int slot = atomicAdd(&curp[d], 1);
  col[slot] = s;
}

// ---------------- GEMM1 (MFMA): H1'[n+1,128](fp8) = dis * (x @ W1) ----------------
// 512 threads, 128 rows/block. W staged once in LDS (one barrier); A
// fragments loaded directly from global in MFMA layout.
__global__ __launch_bounds__(512) void gemm1_k(const void* __restrict__ xv,
                                               const ushortT* __restrict__ Wt1,
                                               const float* __restrict__ dis,
                                               ucharT* __restrict__ Hb8, int n) {
  __shared__ ushortT sW[128 * 132];
  const bool isbf = probe_isbf(xv);
  const int tid = threadIdx.x;
  // stage Wt1 (coalesced 16B): 128 rows x 128 k = 4096 ushort4 chunks
  for (int i = tid; i < 4096; i += 512) {
    int nn = i >> 5, k4 = (i & 31) * 4;
    *(ushort4*)&sW[nn * 132 + k4] = *(const ushort4*)&Wt1[nn * 128 + k4];
  }
  __syncthreads();

  const int wave = tid >> 6;
  const int lane = tid & 63;
  const int m = lane & 15;
  const int quad = lane >> 4;
  const int row = blockIdx.x * 128 + wave * 16 + m;
  const int rowc = min(row, n - 1);  // clamp keeps loads in-bounds; OOB rows masked at store

  float4v acc[8];
#pragma unroll
  for (int t = 0; t < 8; ++t) acc[t] = (float4v)(0.f);

  if (isbf) {
    const ushortT* xp = (const ushortT*)xv + (size_t)rowc * 128 + quad * 8;
#pragma unroll
    for (int kc = 0; kc < 4; ++kc) {
      short8v af = *(const short8v*)(xp + kc * 32);
#pragma unroll
      for (int nb = 0; nb < 8; ++nb) {
        short8v bf = *(const short8v*)&sW[(nb * 16 + m) * 132 + kc * 32 + quad * 8];
        acc[nb] = __builtin_amdgcn_mfma_f32_16x16x32_bf16(af, bf, acc[nb], 0, 0, 0);
      }
    }
  } else {
    const float* xp = (const float*)xv + (size_t)rowc * 128 + quad * 8;
#pragma unroll
    for (int kc = 0; kc < 4; ++kc) {
      float4 lo = *(const float4*)(xp + kc * 32);
      float4 hi = *(const float4*)(xp + kc * 32 + 4);
      short8v af;
      af[0] = (short)f2bf(lo.x); af[1] = (short)f2bf(lo.y);
      af[2] = (short)f2bf(lo.z); af[3] = (short)f2bf(lo.w);
      af[4] = (short)f2bf(hi.x); af[5] = (short)f2bf(hi.y);
      af[6] = (short)f2bf(hi.z); af[7] = (short)f2bf(hi.w);
#pragma unroll
      for (int nb = 0; nb < 8; ++nb) {
        short8v bf = *(const short8v*)&sW[(nb * 16 + m) * 132 + kc * 32 + quad * 8];
        acc[nb] = __builtin_amdgcn_mfma_f32_16x16x32_bf16(af, bf, acc[nb], 0, 0, 0);
      }
    }
  }

  // D: row = blk*128 + wave*16 + quad*4 + r, col = nb*16 + m; store dis*val fp8
  // row n (sentinel) gets explicit zeros.
#pragma unroll
  for (int r = 0; r < 4; ++r) {
    int grow = blockIdx.x * 128 + wave * 16 + quad * 4 + r;
    if (grow <= n) {
      float sc = (grow < n) ? dis[grow] : 0.f;
#pragma unroll
      for (int nb = 0; nb < 8; ++nb)
        Hb8[(size_t)grow * 128 + nb * 16 + m] =
            (grow < n) ? f2fp8(sc * acc[nb][r]) : (ucharT)0;
    }
  }
}

// ---------------- agg1: A = relu(din*(sum H1'[s] + H1'[i]) + b1) ----------------
// quad-owns-node; octet-split: octet o (8 lanes) handles edges of parity o,
// 16 ch/lane via uint4 gathers. col pipeline one batch ahead. Cross-octet
// merge via shfl_xor(8). Pad -> sentinel n.
__global__ __launch_bounds__(256) void agg1_k(const ucharT* __restrict__ Hb8,
                                              const int* __restrict__ col,
                                              const int2* __restrict__ rpc,
                                              const float* __restrict__ dis,
                                              const void* __restrict__ b1v,
                                              const void* __restrict__ xv,
                                              ushortT* __restrict__ Ab, int n) {
  const bool isbf = probe_isbf(xv);
  const int tid = threadIdx.x;
  const int lane = tid & 63;
  const int wave = tid >> 6;
  const int quad = lane >> 4;
  const int o = (lane >> 3) & 1;     // octet within quad
  const int c16 = (lane & 7) * 16;   // 16-channel slice
  const int node = blockIdx.x * 16 + wave * 4 + quad;
  const bool valid = node < n;
  const int nd = valid ? node : (n - 1);

  const int2 rc = rpc[nd];
  const int start = rc.x;
  const int cnt = valid ? rc.y : 0;
  const float din = dis[nd];

  // hoisted self-row + bias (latency hides under the edge loop)
  const uint4 hsp = *(const uint4*)&Hb8[((unsigned)(valid ? node : n) << 7) + (unsigned)c16];
  float b[16];
  if (isbf) {
    ushort8v b0 = *(const ushort8v*)((const ushortT*)b1v + c16);
    ushort8v b1 = *(const ushort8v*)((const ushortT*)b1v + c16 + 8);
#pragma unroll
    for (int k = 0; k < 8; ++k) { b[k] = bf2f(b0[k]); b[8 + k] = bf2f(b1[k]); }
  } else {
    const float* bf = (const float*)b1v + c16;
#pragma unroll
    for (int k = 0; k < 16; ++k) b[k] = bf[k];
  }

  // wave-uniform loop bound = max degree among the 4 quads
  int cmax = cnt;
  cmax = max(cmax, __shfl_xor(cmax, 16));
  cmax = max(cmax, __shfl_xor(cmax, 32));
  const int cmaxs = __builtin_amdgcn_readfirstlane(cmax);

  float2v acc[8];
#pragma unroll
  for (int k = 0; k < 8; ++k) acc[k] = (float2v)(0.f);

  // col pipeline: this octet's next 4 edges (parity o)
  int nxt[4];
#pragma unroll
  for (int u = 0; u < 4; ++u) nxt[u] = col[start + 2 * u + o];  // slack-covered
  for (int e = 0; e < cmaxs; e += 8) {
    int cur[4];
#pragma unroll
    for (int u = 0; u < 4; ++u) cur[u] = nxt[u];
#pragma unroll
    for (int u = 0; u < 4; ++u) nxt[u] = col[start + e + 8 + 2 * u + o];
#pragma unroll
    for (int u = 0; u < 4; ++u) {
      const int ee = e + 2 * u + o;
      int s = (ee < cnt) ? cur[u] : n;  // sentinel: zero row
      const uint4 h = *(const uint4*)&Hb8[((unsigned)s << 7) + (unsigned)c16];
      acc[0] += __builtin_amdgcn_cvt_pk_f32_fp8(h.x, false);
      acc[1] += __builtin_amdgcn_cvt_pk_f32_fp8(h.x, true);
      acc[2] += __builtin_amdgcn_cvt_pk_f32_fp8(h.y, false);
      acc[3] += __builtin_amdgcn_cvt_pk_f32_fp8(h.y, true);
      acc[4] += __builtin_amdgcn_cvt_pk_f32_fp8(h.z, false);
      acc[5] += __builtin_amdgcn_cvt_pk_f32_fp8(h.z, true);
      acc[6] += __builtin_amdgcn_cvt_pk_f32_fp8(h.w, false);
      acc[7] += __builtin_amdgcn_cvt_pk_f32_fp8(h.w, true);
    }
  }

  // merge octets
#pragma unroll
  for (int k = 0; k < 8; ++k) {
    float t0 = __shfl_xor(acc[k][0], 8);
    float t1 = __shfl_xor(acc[k][1], 8);
    acc[k][0] += t0;
    acc[k][1] += t1;
  }

  if (valid && o == 0) {
    // decode self-row: word w -> hs[4w..4w+3], matching acc index order
    float hs[16];
    {
      const unsigned int w4[4] = {hsp.x, hsp.y, hsp.z, hsp.w};
#pragma unroll
      for (int w = 0; w < 4; ++w) {
        float2v p0 = __builtin_amdgcn_cvt_pk_f32_fp8(w4[w], false);
        float2v p1 = __builtin_amdgcn_cvt_pk_f32_fp8(w4[w], true);
        hs[4 * w] = p0[0]; hs[4 * w + 1] = p0[1];
        hs[4 * w + 2] = p1[0]; hs[4 * w + 3] = p1[1];
      }
    }
    ushort8v o0, o1;
#pragma unroll
    for (int k = 0; k < 4; ++k) {
      o0[2 * k]     = f2bf(fmaxf(fmaf(din, acc[k][0] + hs[2 * k],     b[2 * k]),     0.f));
      o0[2 * k + 1] = f2bf(fmaxf(fmaf(din, acc[k][1] + hs[2 * k + 1], b[2 * k + 1]), 0.f));
    }
#pragma unroll
    for (int k = 4; k < 8; ++k) {
      o1[2 * (k - 4)]     = f2bf(fmaxf(fmaf(din, acc[k][0] + hs[2 * k],     b[2 * k]),     0.f));
      o1[2 * (k - 4) + 1] = f2bf(fmaxf(fmaf(din, acc[k][1] + hs[2 * k + 1], b[2 * k + 1]), 0.f));
    }
    *(ushort8v*)&Ab[(size_t)node * 128 + c16] = o0;
    *(ushort8v*)&Ab[(size_t)node * 128 + c16 + 8] = o1;
  }
}

// ---------------- GEMM2 (MFMA): H2'[n+1,64](fp8) = dis * (A @ W2) ----------------
// 512 threads, 128 rows/block; W staged once; A fragments direct from global.
__global__ __launch_bounds__(512) void gemm2_k(const ushortT* __restrict__ Ab,
                                               const ushortT* __restrict__ Wt2,
                                               const float* __restrict__ dis,
                                               ucharT* __restrict__ H2b8, int n) {
  __shared__ ushortT sW[64 * 132];
  const int tid = threadIdx.x;
  // stage Wt2 (coalesced 16B): 64 rows x 128 k = 2048 ushort4 chunks
  for (int i = tid; i < 2048; i += 512) {
    int nn = i >> 5, k4 = (i & 31) * 4;
    *(ushort4*)&sW[nn * 132 + k4] = *(const ushort4*)&Wt2[nn * 128 + k4];
  }
  __syncthreads();

  const int wave = tid >> 6;
  const int lane = tid & 63;
  const int m = lane & 15;
  const int quad = lane >> 4;
  const int row = blockIdx.x * 128 + wave * 16 + m;
  const int rowc = min(row, n - 1);

  float4v acc[4];
#pragma unroll
  for (int t = 0; t < 4; ++t) acc[t] = (float4v)(0.f);

  const ushortT* ap = Ab + (size_t)rowc * 128 + quad * 8;
#pragma unroll
  for (int kc = 0; kc < 4; ++kc) {
    short8v af = *(const short8v*)(ap + kc * 32);
#pragma unroll
    for (int nb = 0; nb < 4; ++nb) {
      short8v bf = *(const short8v*)&sW[(nb * 16 + m) * 132 + kc * 32 + quad * 8];
      acc[nb] = __builtin_amdgcn_mfma_f32_16x16x32_bf16(af, bf, acc[nb], 0, 0, 0);
    }
  }

#pragma unroll
  for (int r = 0; r < 4; ++r) {
    int grow = blockIdx.x * 128 + wave * 16 + quad * 4 + r;
    if (grow <= n) {
      float sc = (grow < n) ? dis[grow] : 0.f;
#pragma unroll
      for (int nb = 0; nb < 4; ++nb)
        H2b8[(size_t)grow * 64 + nb * 16 + m] =
            (grow < n) ? f2fp8(sc * acc[nb][r]) : (ucharT)0;
    }
  }
}

// ---------------- agg2 + log_softmax -> out ----------------
// quad-owns-node; octet-split, 8 ch/lane via uint2 gathers; col pipeline;
// cross-octet merge shfl_xor(8); softmax reduce over octet (1,2,4).
__global__ __launch_bounds__(256) void agg2_k(const ucharT* __restrict__ H2b8,
                                              const int* __restrict__ col,
                                              const int2* __restrict__ rpc,
                                              const float* __restrict__ dis,
                                              const void* __restrict__ b2v,
                                              const void* __restrict__ xv,
                                              void* __restrict__ outv, int n) {
  const bool isbf = probe_isbf(xv);
  const int tid = threadIdx.x;
  const int lane = tid & 63;
  const int wave = tid >> 6;
  const int quad = lane >> 4;
  const int o = (lane >> 3) & 1;
  const int c8 = (lane & 7) * 8;   // 8-channel slice
  const int node = blockIdx.x * 16 + wave * 4 + quad;
  const bool valid = node < n;
  const int nd = valid ? node : (n - 1);

  const int2 rc = rpc[nd];
  const int start = rc.x;
  const int cnt = valid ? rc.y : 0;
  const float din = dis[nd];

  const uint2 hsp =
      *(const uint2*)&H2b8[((unsigned)(valid ? node : n) << 6) + (unsigned)c8];
  float b[8];
  if (isbf) {
    ushort8v bb = *(const ushort8v*)((const ushortT*)b2v + c8);
#pragma unroll
    for (int k = 0; k < 8; ++k) b[k] = bf2f(bb[k]);
  } else {
    const float* bf = (const float*)b2v + c8;
#pragma unroll
    for (int k = 0; k < 8; ++k) b[k] = bf[k];
  }

  int cmax = cnt;
  cmax = max(cmax, __shfl_xor(cmax, 16));
  cmax = max(cmax, __shfl_xor(cmax, 32));
  const int cmaxs = __builtin_amdgcn_readfirstlane(cmax);

  float2v acc[4];
#pragma unroll
  for (int k = 0; k < 4; ++k) acc[k] = (float2v)(0.f);

  int nxt[4];
#pragma unroll
  for (int u = 0; u < 4; ++u) nxt[u] = col[start + 2 * u + o];
  for (int e = 0; e < cmaxs; e += 8) {
    int cur[4];
#pragma unroll
    for (int u = 0; u < 4; ++u) cur[u] = nxt[u];
#pragma unroll
    for (int u = 0; u < 4; ++u) nxt[u] = col[start + e + 8 + 2 * u + o];
#pragma unroll
    for (int u = 0; u < 4; ++u) {
      const int ee = e + 2 * u + o;
      int s = (ee < cnt) ? cur[u] : n;  // sentinel: zero row
      const uint2 h = *(const uint2*)&H2b8[((unsigned)s << 6) + (unsigned)c8];
      acc[0] += __builtin_amdgcn_cvt_pk_f32_fp8(h.x, false);
      acc[1] += __builtin_amdgcn_cvt_pk_f32_fp8(h.x, true);
      acc[2] += __builtin_amdgcn_cvt_pk_f32_fp8(h.y, false);
      acc[3] += __builtin_amdgcn_cvt_pk_f32_fp8(h.y, true);
    }
  }

#pragma unroll
  for (int k = 0; k < 4; ++k) {
    float t0 = __shfl_xor(acc[k][0], 8);
    float t1 = __shfl_xor(acc[k][1], 8);
    acc[k][0] += t0;
    acc[k][1] += t1;
  }

  // decode self-row (2 words -> 8 ch, matching acc order)
  float hs[8];
  {
    float2v p0 = __builtin_amdgcn_cvt_pk_f32_fp8(hsp.x, false);
    float2v p1 = __builtin_amdgcn_cvt_pk_f32_fp8(hsp.x, true);
    float2v p2 = __builtin_amdgcn_cvt_pk_f32_fp8(hsp.y, false);
    float2v p3 = __builtin_amdgcn_cvt_pk_f32_fp8(hsp.y, true);
    hs[0] = p0[0]; hs[1] = p0[1]; hs[2] = p1[0]; hs[3] = p1[1];
    hs[4] = p2[0]; hs[5] = p2[1]; hs[6] = p3[0]; hs[7] = p3[1];
  }
  float v[8];
#pragma unroll
  for (int k = 0; k < 4; ++k) {
    v[2 * k]     = fmaf(din, acc[k][0] + hs[2 * k],     b[2 * k]);
    v[2 * k + 1] = fmaf(din, acc[k][1] + hs[2 * k + 1], b[2 * k + 1]);
  }

  // log_softmax over 64 channels: local 8 + octet (8-lane) reduce
  float mx = v[0];
#pragma unroll
  for (int k = 1; k < 8; ++k) mx = fmaxf(mx, v[k]);
  for (int off = 1; off < 8; off <<= 1) mx = fmaxf(mx, __shfl_xor(mx, off));
  float ssum = 0.f;
#pragma unroll
  for (int k = 0; k < 8; ++k) ssum += __expf(v[k] - mx);
  for (int off = 1; off < 8; off <<= 1) ssum += __shfl_xor(ssum, off);
  const float lse = mx + __logf(ssum);

  if (valid && o == 0) {
    if (isbf) {
      ushort8v ov;
#pragma unroll
      for (int k = 0; k < 8; ++k) ov[k] = f2bf(v[k] - lse);
      *(ushort8v*)((__hip_bfloat16*)outv + (size_t)node * 64 + c8) = ov;
    } else {
      float4 o0 = make_float4(v[0] - lse, v[1] - lse, v[2] - lse, v[3] - lse);
      float4 o1 = make_float4(v[4] - lse, v[5] - lse, v[6] - lse, v[7] - lse);
      *(float4*)((float*)outv + (size_t)node * 64 + c8) = o0;
      *(float4*)((float*)outv + (size_t)node * 64 + c8 + 4) = o1;
    }
  }
}

// ---------------- launch ----------------

extern "C" void kernel_launch(void* const* d_in, const int* in_sizes, int n_in,
                              void* d_out, int out_size, void* d_ws, size_t ws_size,
                              hipStream_t stream) {
  const void* x  = d_in[0];
  const int*  ei = (const int*)d_in[1];
  const void* W1 = d_in[2];
  const void* b1 = d_in[3];
  const void* W2 = d_in[4];
  const void* b2 = d_in[5];

  const int n = in_sizes[0] / 128;
  const int E = in_sizes[1] / 2;
  const int B = (n + 255) >> 8;  // buckets of 256 nodes
  const int* srcv = ei;      // edge_index[0]
  const int* dstv = ei + E;  // edge_index[1]

  // workspace layout (~50 MB), 256B-aligned sections
  char* p = (char*)d_ws;
  auto alloc = [&](size_t bytes) {
    char* q = p;
    p += (bytes + 255) & ~(size_t)255;
    return q;
  };
  ucharT* Hb8 = (ucharT*)alloc((size_t)(n + 1) * 128);      // H1' fp8, +sentinel row
  ucharT* H2b8 = (ucharT*)alloc((size_t)(n + 1) * 64);      // H2' fp8, +sentinel row
  ushortT* Ab = (ushortT*)alloc((size_t)n * 128 * 2);       // A bf16
  float* dis = (float*)alloc((size_t)n * 4);
  int2* rpc = (int2*)alloc((size_t)n * 8);                  // (row_ptr, count)
  int* ncnt = (int*)alloc((size_t)B * 256 * 4);             // per-node degree
  int* curp = (int*)alloc((size_t)n * 4);                   // scatter cursors
  ushortT* Wt1 = (ushortT*)alloc(16384 * 2);
  ushortT* Wt2 = (ushortT*)alloc(8192 * 2);
  int* col = (int*)alloc(((size_t)E + 4096) * 4);  // slack covers pipeline over-read

  (void)hipMemsetAsync(ncnt, 0, (size_t)B * 256 * sizeof(int), stream);

  const int eBlocks = (E + 255) / 256;
  const int hBlocks = max(eBlocks, 96);  // >=96 so wprep is fully covered

  bhist_k<<<hBlocks, 256, 0, stream>>>(dstv, E, W1, W2, x, Wt1, Wt2, ncnt);
  rp_k<<<B, 256, 0, stream>>>(ncnt, n, rpc, dis, curp);
  scat_k<<<eBlocks, 256, 0, stream>>>(srcv, dstv, E, curp, col);

  // grids cover n+1 rows so the sentinel row is written even when n%128==0
  gemm1_k<<<(n + 128) / 128, 512, 0, stream>>>(x, Wt1, dis, Hb8, n);
  agg1_k<<<(n + 15) / 16, 256, 0, stream>>>(Hb8, col, rpc, dis, b1, x, Ab, n);
  gemm2_k<<<(n + 128) / 128, 512, 0, stream>>>(Ab, Wt2, dis, H2b8, n);
  agg2_k<<<(n + 15) / 16, 256, 0, stream>>>(H2b8, col, rpc, dis, b2, x, d_out, n);
}

// Round 12
// 226.798 us; speedup vs baseline: 1.8998x; 1.8998x over previous
//
#include <hip/hip_runtime.h>
#include <hip/hip_bf16.h>

// GCN 2-layer forward on MI355X.
// Round-21: REVERT to the R18 kernel — verified session best (228.9us).
// R20 post-mortem: direct-scatter build regressed 230->431us. scat_k's
// 1.6M random global atomics + scattered 4B col stores caused 105MB of
// writes for a 6.4MB array (16x line-granularity amplification). The
// bucketed build (bhist+wprep/bscan/bin/csr) exists precisely to turn
// random scatter into LDS-staged bucket-local coalesced writes. Session
// evidence now covers every component from multiple directions:
//  - aggs: unroll-8 (+4us), col-pipeline (+1us), octet-split (flat),
//    ILP-4 (spill, -85us), block fusion (TLP loss) -> at per-XCD
//    compulsory-fetch / gather-latency floor (agg1 FETCH 90MB ~ 0.88x
//    8-XCD table pull).
//  - GEMMs: direct-from-global A-fragments + single W stage, <10us each.
//  - build: padded-CAP (-15us) and direct-scatter (-200us) both lost to
//    the compact bucketed chain.
// R18 = R16 + col software-pipeline: compact bucketed CSR, quad-owns-node
// aggs with unroll-8, sentinel cndmask, pre-scaled fp8 features.

typedef unsigned short ushortT;
typedef unsigned char ucharT;
typedef __attribute__((ext_vector_type(8))) short short8v;        // 8 bf16 (4 VGPR)
typedef __attribute__((ext_vector_type(4))) float float4v;        // MFMA C/D
typedef __attribute__((ext_vector_type(2))) float float2v;
typedef __attribute__((ext_vector_type(8))) unsigned short ushort8v;

__device__ __forceinline__ float bf2f(ushortT u) {
  union { unsigned int i; float f; } x;
  x.i = ((unsigned int)u) << 16;
  return x.f;
}

__device__ __forceinline__ ushortT f2bf(float f) {
  __hip_bfloat16 h = __float2bfloat16(f);  // RNE
  return *(ushortT*)&h;
}

__device__ __forceinline__ ucharT f2fp8(float f) {
  unsigned int w = __builtin_amdgcn_cvt_pk_fp8_f32(f, f, 0, false);
  return (ucharT)(w & 0xff);
}

// decode 8 fp8 bytes (two dwords) into f[0..7]
__device__ __forceinline__ void fp8x8_to_f32(unsigned int lo, unsigned int hi,
                                             float* f) {
  float2v p0 = __builtin_amdgcn_cvt_pk_f32_fp8(lo, false);  // bytes 0,1
  float2v p1 = __builtin_amdgcn_cvt_pk_f32_fp8(lo, true);   // bytes 2,3
  float2v p2 = __builtin_amdgcn_cvt_pk_f32_fp8(hi, false);
  float2v p3 = __builtin_amdgcn_cvt_pk_f32_fp8(hi, true);
  f[0] = p0[0]; f[1] = p0[1]; f[2] = p1[0]; f[3] = p1[1];
  f[4] = p2[0]; f[5] = p2[1]; f[6] = p3[0]; f[7] = p3[1];
}

// decode 4 fp8 bytes (one dword) into f[0..3]
__device__ __forceinline__ void fp8x4_to_f32(unsigned int w, float* f) {
  float2v p0 = __builtin_amdgcn_cvt_pk_f32_fp8(w, false);
  float2v p1 = __builtin_amdgcn_cvt_pk_f32_fp8(w, true);
  f[0] = p0[0]; f[1] = p0[1]; f[2] = p1[0]; f[3] = p1[1];
}

// wave-uniform dtype probe: interpret x's first 64 halfwords as bf16 and
// check sanity. Every wave reads the same hot 128B line. Deterministic.
__device__ __forceinline__ bool probe_isbf(const void* xv) {
  const ushortT* xr = (const ushortT*)xv;
  const int lane = threadIdx.x & 63;
  float v = bf2f(xr[lane]);
  bool sane = isfinite(v) && fabsf(v) < 1e4f;
  return __ballot(sane) == ~0ull;
}

// ---------------- bhist + wprep (merged): bucket histogram & W transposes ----------------
// bucket b = dst >> 8 (256 nodes/bucket), B = ceil(n/256)
__global__ __launch_bounds__(256) void bhist_k(const int* __restrict__ dst, int E, int B,
                                               int* __restrict__ gbc,
                                               const void* __restrict__ W1v,
                                               const void* __restrict__ W2v,
                                               const void* __restrict__ xv,
                                               ushortT* __restrict__ Wt1,
                                               ushortT* __restrict__ Wt2) {
  __shared__ int h[512];
  const int tid = threadIdx.x;
  // wprep part: blocks 0..95 (24576 elements, block-uniform branch)
  const int gi = blockIdx.x * 256 + tid;
  if (gi < 24576) {
    const bool isbf = probe_isbf(xv);
    if (gi < 16384) {
      int nn = gi & 127, k = gi >> 7;   // read W1[k][nn] coalesced in nn
      ushortT v = isbf ? ((const ushortT*)W1v)[k * 128 + nn]
                       : f2bf(((const float*)W1v)[k * 128 + nn]);
      Wt1[nn * 128 + k] = v;
    } else {
      int j = gi - 16384;
      int nn = j & 63, k = j >> 6;      // read W2[k][nn] coalesced in nn
      ushortT v = isbf ? ((const ushortT*)W2v)[k * 64 + nn]
                       : f2bf(((const float*)W2v)[k * 64 + nn]);
      Wt2[nn * 128 + k] = v;
    }
  }
  // histogram part
  for (int i = tid; i < B; i += 256) h[i] = 0;
  __syncthreads();
  const int i0 = blockIdx.x * 8192;
  const int iend = min(i0 + 8192, E);
  for (int i = i0 + tid; i < iend; i += 256) atomicAdd(&h[dst[i] >> 8], 1);
  __syncthreads();
  for (int i = tid; i < B; i += 256)
    if (h[i]) atomicAdd(&gbc[i], h[i]);
}

__global__ __launch_bounds__(256) void bscan_k(const int* __restrict__ gbc, int B,
                                               int* __restrict__ bbase,
                                               int* __restrict__ gcur) {
  __shared__ int p[256];
  const int t = threadIdx.x;
  int a = (2 * t < B) ? gbc[2 * t] : 0;
  int b = (2 * t + 1 < B) ? gbc[2 * t + 1] : 0;
  const int sum = a + b;
  p[t] = sum;
  __syncthreads();
  int run = sum;
  for (int off = 1; off < 256; off <<= 1) {
    int v = (t >= off) ? p[t - off] : 0;
    __syncthreads();
    run += v;
    p[t] = run;
    __syncthreads();
  }
  const int excl = run - sum;
  if (2 * t < B) { bbase[2 * t] = excl; gcur[2 * t] = excl; }
  if (2 * t + 1 < B) { bbase[2 * t + 1] = excl + a; gcur[2 * t + 1] = excl + a; }
}

__global__ __launch_bounds__(256) void bin_k(const int* __restrict__ srcv,
                                             const int* __restrict__ dstv, int E, int B,
                                             int* __restrict__ gcur,
                                             int* __restrict__ tmp) {
  __shared__ int hist[512];
  __shared__ int base[512];
  const int tid = threadIdx.x;
  const int i0 = blockIdx.x * 8192;
  const int iend = min(i0 + 8192, E);
  for (int i = tid; i < B; i += 256) hist[i] = 0;
  __syncthreads();
  for (int i = i0 + tid; i < iend; i += 256) atomicAdd(&hist[dstv[i] >> 8], 1);
  __syncthreads();
  for (int i = tid; i < B; i += 256) {
    int h = hist[i];
    base[i] = h ? atomicAdd(&gcur[i], h) : 0;
    hist[i] = 0;  // reuse as local cursor
  }
  __syncthreads();
  for (int i = i0 + tid; i < iend; i += 256) {
    int d = dstv[i];
    int s = srcv[i];
    int b = d >> 8;
    int l = atomicAdd(&hist[b], 1);
    tmp[base[b] + l] = s | ((d & 255) << 17);  // n < 2^17 required (n=100k)
  }
}

// wg per bucket: per-node counts, (row_ptr,count) pack, dis, in-bucket scatter
__global__ __launch_bounds__(256) void csr_k(const int* __restrict__ tmp,
                                             const int* __restrict__ bbase,
                                             const int* __restrict__ gbc, int n,
                                             int2* __restrict__ rpc,
                                             float* __restrict__ dis,
                                             int* __restrict__ col) {
  __shared__ int lhist[256];
  __shared__ int lexcl[256];
  const int b = blockIdx.x;
  const int tid = threadIdx.x;
  const int e0 = bbase[b];
  const int e1 = e0 + gbc[b];
  lhist[tid] = 0;
  __syncthreads();
  for (int i = e0 + tid; i < e1; i += 256) atomicAdd(&lhist[tmp[i] >> 17], 1);
  __syncthreads();
  const int v = lhist[tid];
  int run = v;
  lexcl[tid] = run;
  __syncthreads();
  for (int off = 1; off < 256; off <<= 1) {
    int t = (tid >= off) ? lexcl[tid - off] : 0;
    __syncthreads();
    run += t;
    lexcl[tid] = run;
    __syncthreads();
  }
  const int excl = run - v;
  const int node = (b << 8) + tid;
  if (node < n) {
    rpc[node] = make_int2(e0 + excl, v);
    dis[node] = rsqrtf((float)(v + 1));
  }
  lhist[tid] = 0;
  lexcl[tid] = excl;
  __syncthreads();
  for (int i = e0 + tid; i < e1; i += 256) {
    int p = tmp[i];
    int dloc = p >> 17;
    int s = p & 131071;
    int l = atomicAdd(&lhist[dloc], 1);
    col[e0 + lexcl[dloc] + l] = s;
  }
}

// ---------------- GEMM1 (MFMA): H1'[n+1,128](fp8) = dis * (x @ W1) ----------------
// 512 threads, 128 rows/block. W staged once in LDS (one barrier); A
// fragments loaded directly from global in MFMA layout.
__global__ __launch_bounds__(512) void gemm1_k(const void* __restrict__ xv,
                                               const ushortT* __restrict__ Wt1,
                                               const float* __restrict__ dis,
                                               ucharT* __restrict__ Hb8, int n) {
  __shared__ ushortT sW[128 * 132];
  const bool isbf = probe_isbf(xv);
  const int tid = threadIdx.x;
  // stage Wt1 (coalesced 16B): 128 rows x 128 k = 4096 ushort4 chunks
  for (int i = tid; i < 4096; i += 512) {
    int nn = i >> 5, k4 = (i & 31) * 4;
    *(ushort4*)&sW[nn * 132 + k4] = *(const ushort4*)&Wt1[nn * 128 + k4];
  }
  __syncthreads();

  const int wave = tid >> 6;
  const int lane = tid & 63;
  const int m = lane & 15;
  const int quad = lane >> 4;
  const int row = blockIdx.x * 128 + wave * 16 + m;
  const int rowc = min(row, n - 1);  // clamp keeps loads in-bounds; OOB rows masked at store

  float4v acc[8];
#pragma unroll
  for (int t = 0; t < 8; ++t) acc[t] = (float4v)(0.f);

  if (isbf) {
    const ushortT* xp = (const ushortT*)xv + (size_t)rowc * 128 + quad * 8;
#pragma unroll
    for (int kc = 0; kc < 4; ++kc) {
      short8v af = *(const short8v*)(xp + kc * 32);
#pragma unroll
      for (int nb = 0; nb < 8; ++nb) {
        short8v bf = *(const short8v*)&sW[(nb * 16 + m) * 132 + kc * 32 + quad * 8];
        acc[nb] = __builtin_amdgcn_mfma_f32_16x16x32_bf16(af, bf, acc[nb], 0, 0, 0);
      }
    }
  } else {
    const float* xp = (const float*)xv + (size_t)rowc * 128 + quad * 8;
#pragma unroll
    for (int kc = 0; kc < 4; ++kc) {
      float4 lo = *(const float4*)(xp + kc * 32);
      float4 hi = *(const float4*)(xp + kc * 32 + 4);
      short8v af;
      af[0] = (short)f2bf(lo.x); af[1] = (short)f2bf(lo.y);
      af[2] = (short)f2bf(lo.z); af[3] = (short)f2bf(lo.w);
      af[4] = (short)f2bf(hi.x); af[5] = (short)f2bf(hi.y);
      af[6] = (short)f2bf(hi.z); af[7] = (short)f2bf(hi.w);
#pragma unroll
      for (int nb = 0; nb < 8; ++nb) {
        short8v bf = *(const short8v*)&sW[(nb * 16 + m) * 132 + kc * 32 + quad * 8];
        acc[nb] = __builtin_amdgcn_mfma_f32_16x16x32_bf16(af, bf, acc[nb], 0, 0, 0);
      }
    }
  }

  // D: row = blk*128 + wave*16 + quad*4 + r, col = nb*16 + m; store dis*val fp8
  // row n (sentinel) gets explicit zeros.
#pragma unroll
  for (int r = 0; r < 4; ++r) {
    int grow = blockIdx.x * 128 + wave * 16 + quad * 4 + r;
    if (grow <= n) {
      float sc = (grow < n) ? dis[grow] : 0.f;
#pragma unroll
      for (int nb = 0; nb < 8; ++nb)
        Hb8[(size_t)grow * 128 + nb * 16 + m] =
            (grow < n) ? f2fp8(sc * acc[nb][r]) : (ucharT)0;
    }
  }
}

// ---------------- agg1: A = relu(din*(sum H1'[s] + H1'[i]) + b1) ----------------
// quad-owns-node: each 16-lane quarter owns one node. 8 ch/lane (8B fp8
// gather), edge unroll-8 with col loads software-pipelined one batch
// ahead (col latency hides under gathers). Pad slots -> sentinel row n.
__global__ __launch_bounds__(256) void agg1_k(const ucharT* __restrict__ Hb8,
                                              const int* __restrict__ col,
                                              const int2* __restrict__ rpc,
                                              const float* __restrict__ dis,
                                              const void* __restrict__ b1v,
                                              const void* __restrict__ xv,
                                              ushortT* __restrict__ Ab, int n) {
  const bool isbf = probe_isbf(xv);
  const int tid = threadIdx.x;
  const int lane = tid & 63;
  const int wave = tid >> 6;
  const int quad = lane >> 4;
  const int m = lane & 15;
  const int c8 = m * 8;
  const int node = blockIdx.x * 16 + wave * 4 + quad;
  const bool valid = node < n;
  const int nd = valid ? node : (n - 1);

  const int2 rc = rpc[nd];
  const int start = rc.x;
  const int cnt = valid ? rc.y : 0;
  const float din = dis[nd];

  // hoisted self-row + bias (latency hides under the edge loop)
  const uint2 hsp = *(const uint2*)&Hb8[((unsigned)(valid ? node : n) << 7) + (unsigned)c8];
  float b[8];
  if (isbf) {
    ushort8v bb = *(const ushort8v*)((const ushortT*)b1v + c8);
#pragma unroll
    for (int k = 0; k < 8; ++k) b[k] = bf2f(bb[k]);
  } else {
    const float* bf = (const float*)b1v + c8;
#pragma unroll
    for (int k = 0; k < 8; ++k) b[k] = bf[k];
  }

  // wave-uniform loop bound = max degree among the 4 quads
  int cmax = cnt;
  cmax = max(cmax, __shfl_xor(cmax, 16));
  cmax = max(cmax, __shfl_xor(cmax, 32));
  const int cmaxs = __builtin_amdgcn_readfirstlane(cmax);

  float2v acc[4];
#pragma unroll
  for (int k = 0; k < 4; ++k) acc[k] = (float2v)(0.f);

  // software pipeline: col batch e+8 loads issue while batch e gathers run
  int nxt[8];
#pragma unroll
  for (int u = 0; u < 8; ++u) nxt[u] = col[start + u];  // slack-covered
  for (int e = 0; e < cmaxs; e += 8) {
    int cur[8];
#pragma unroll
    for (int u = 0; u < 8; ++u) cur[u] = nxt[u];
#pragma unroll
    for (int u = 0; u < 8; ++u) nxt[u] = col[start + e + 8 + u];
#pragma unroll
    for (int u = 0; u < 8; ++u) {
      const int ee = e + u;
      int s = (ee < cnt) ? cur[u] : n;  // sentinel: zero row
      const uint2 h = *(const uint2*)&Hb8[((unsigned)s << 7) + (unsigned)c8];
      acc[0] += __builtin_amdgcn_cvt_pk_f32_fp8(h.x, false);
      acc[1] += __builtin_amdgcn_cvt_pk_f32_fp8(h.x, true);
      acc[2] += __builtin_amdgcn_cvt_pk_f32_fp8(h.y, false);
      acc[3] += __builtin_amdgcn_cvt_pk_f32_fp8(h.y, true);
    }
  }

  if (valid) {
    float hs[8];
    fp8x8_to_f32(hsp.x, hsp.y, hs);
    ushort8v o;
#pragma unroll
    for (int k = 0; k < 4; ++k) {
      o[2 * k]     = f2bf(fmaxf(fmaf(din, acc[k][0] + hs[2 * k],     b[2 * k]),     0.f));
      o[2 * k + 1] = f2bf(fmaxf(fmaf(din, acc[k][1] + hs[2 * k + 1], b[2 * k + 1]), 0.f));
    }
    *(ushort8v*)&Ab[(size_t)node * 128 + c8] = o;
  }
}

// ---------------- GEMM2 (MFMA): H2'[n+1,64](fp8) = dis * (A @ W2) ----------------
// 512 threads, 128 rows/block; W staged once; A fragments direct from global.
__global__ __launch_bounds__(512) void gemm2_k(const ushortT* __restrict__ Ab,
                                               const ushortT* __restrict__ Wt2,
                                               const float* __restrict__ dis,
                                               ucharT* __restrict__ H2b8, int n) {
  __shared__ ushortT sW[64 * 132];
  const int tid = threadIdx.x;
  // stage Wt2 (coalesced 16B): 64 rows x 128 k = 2048 ushort4 chunks
  for (int i = tid; i < 2048; i += 512) {
    int nn = i >> 5, k4 = (i & 31) * 4;
    *(ushort4*)&sW[nn * 132 + k4] = *(const ushort4*)&Wt2[nn * 128 + k4];
  }
  __syncthreads();

  const int wave = tid >> 6;
  const int lane = tid & 63;
  const int m = lane & 15;
  const int quad = lane >> 4;
  const int row = blockIdx.x * 128 + wave * 16 + m;
  const int rowc = min(row, n - 1);

  float4v acc[4];
#pragma unroll
  for (int t = 0; t < 4; ++t) acc[t] = (float4v)(0.f);

  const ushortT* ap = Ab + (size_t)rowc * 128 + quad * 8;
#pragma unroll
  for (int kc = 0; kc < 4; ++kc) {
    short8v af = *(const short8v*)(ap + kc * 32);
#pragma unroll
    for (int nb = 0; nb < 4; ++nb) {
      short8v bf = *(const short8v*)&sW[(nb * 16 + m) * 132 + kc * 32 + quad * 8];
      acc[nb] = __builtin_amdgcn_mfma_f32_16x16x32_bf16(af, bf, acc[nb], 0, 0, 0);
    }
  }

#pragma unroll
  for (int r = 0; r < 4; ++r) {
    int grow = blockIdx.x * 128 + wave * 16 + quad * 4 + r;
    if (grow <= n) {
      float sc = (grow < n) ? dis[grow] : 0.f;
#pragma unroll
      for (int nb = 0; nb < 4; ++nb)
        H2b8[(size_t)grow * 64 + nb * 16 + m] =
            (grow < n) ? f2fp8(sc * acc[nb][r]) : (ucharT)0;
    }
  }
}

// ---------------- agg2 + log_softmax -> out ----------------
// quad-owns-node; 4 ch/lane (4B fp8 gather), edge unroll-8 with col
// software-pipeline; per-quad softmax (shfl_xor 1..8 in-group).
__global__ __launch_bounds__(256) void agg2_k(const ucharT* __restrict__ H2b8,
                                              const int* __restrict__ col,
                                              const int2* __restrict__ rpc,
                                              const float* __restrict__ dis,
                                              const void* __restrict__ b2v,
                                              const void* __restrict__ xv,
                                              void* __restrict__ outv, int n) {
  const bool isbf = probe_isbf(xv);
  const int tid = threadIdx.x;
  const int lane = tid & 63;
  const int wave = tid >> 6;
  const int quad = lane >> 4;
  const int m = lane & 15;
  const int c4 = m * 4;
  const int node = blockIdx.x * 16 + wave * 4 + quad;
  const bool valid = node < n;
  const int nd = valid ? node : (n - 1);

  const int2 rc = rpc[nd];
  const int start = rc.x;
  const int cnt = valid ? rc.y : 0;
  const float din = dis[nd];

  const unsigned int hsp =
      *(const unsigned int*)&H2b8[((unsigned)(valid ? node : n) << 6) + (unsigned)c4];
  float b[4];
  if (isbf) {
    ushort4 bb = *(const ushort4*)((const ushortT*)b2v + c4);
    b[0] = bf2f(bb.x); b[1] = bf2f(bb.y); b[2] = bf2f(bb.z); b[3] = bf2f(bb.w);
  } else {
    const float* bf = (const float*)b2v + c4;
#pragma unroll
    for (int k = 0; k < 4; ++k) b[k] = bf[k];
  }

  int cmax = cnt;
  cmax = max(cmax, __shfl_xor(cmax, 16));
  cmax = max(cmax, __shfl_xor(cmax, 32));
  const int cmaxs = __builtin_amdgcn_readfirstlane(cmax);

  float2v acc[2];
  acc[0] = (float2v)(0.f);
  acc[1] = (float2v)(0.f);

  int nxt[8];
#pragma unroll
  for (int u = 0; u < 8; ++u) nxt[u] = col[start + u];
  for (int e = 0; e < cmaxs; e += 8) {
    int cur[8];
#pragma unroll
    for (int u = 0; u < 8; ++u) cur[u] = nxt[u];
#pragma unroll
    for (int u = 0; u < 8; ++u) nxt[u] = col[start + e + 8 + u];
#pragma unroll
    for (int u = 0; u < 8; ++u) {
      const int ee = e + u;
      int s = (ee < cnt) ? cur[u] : n;  // sentinel: zero row
      const unsigned int h = *(const unsigned int*)&H2b8[((unsigned)s << 6) + (unsigned)c4];
      acc[0] += __builtin_amdgcn_cvt_pk_f32_fp8(h, false);
      acc[1] += __builtin_amdgcn_cvt_pk_f32_fp8(h, true);
    }
  }

  float hs[4];
  fp8x4_to_f32(hsp, hs);
  float v[4];
  v[0] = fmaf(din, acc[0][0] + hs[0], b[0]);
  v[1] = fmaf(din, acc[0][1] + hs[1], b[1]);
  v[2] = fmaf(din, acc[1][0] + hs[2], b[2]);
  v[3] = fmaf(din, acc[1][1] + hs[3], b[3]);

  // log_softmax over 64 channels: local 4 + 16-lane group reduce (in-quad)
  float mx = fmaxf(fmaxf(v[0], v[1]), fmaxf(v[2], v[3]));
  for (int off = 1; off < 16; off <<= 1) mx = fmaxf(mx, __shfl_xor(mx, off));
  float ssum = __expf(v[0] - mx) + __expf(v[1] - mx) + __expf(v[2] - mx) + __expf(v[3] - mx);
  for (int off = 1; off < 16; off <<= 1) ssum += __shfl_xor(ssum, off);
  const float lse = mx + __logf(ssum);

  if (valid) {
    if (isbf) {
      ushort4 o;
      o.x = f2bf(v[0] - lse); o.y = f2bf(v[1] - lse);
      o.z = f2bf(v[2] - lse); o.w = f2bf(v[3] - lse);
      *(ushort4*)((__hip_bfloat16*)outv + (size_t)node * 64 + c4) = o;
    } else {
      float4 o = make_float4(v[0] - lse, v[1] - lse, v[2] - lse, v[3] - lse);
      *(float4*)((float*)outv + (size_t)node * 64 + c4) = o;
    }
  }
}

// ---------------- launch ----------------

extern "C" void kernel_launch(void* const* d_in, const int* in_sizes, int n_in,
                              void* d_out, int out_size, void* d_ws, size_t ws_size,
                              hipStream_t stream) {
  const void* x  = d_in[0];
  const int*  ei = (const int*)d_in[1];
  const void* W1 = d_in[2];
  const void* b1 = d_in[3];
  const void* W2 = d_in[4];
  const void* b2 = d_in[5];

  const int n = in_sizes[0] / 128;
  const int E = in_sizes[1] / 2;
  const int B = (n + 255) >> 8;  // buckets of 256 nodes
  const int* srcv = ei;      // edge_index[0]
  const int* dstv = ei + E;  // edge_index[1]

  // workspace layout (~60 MB), 256B-aligned sections
  char* p = (char*)d_ws;
  auto alloc = [&](size_t bytes) {
    char* q = p;
    p += (bytes + 255) & ~(size_t)255;
    return q;
  };
  ucharT* Hb8 = (ucharT*)alloc((size_t)(n + 1) * 128);      // H1' fp8, +sentinel row
  ucharT* H2b8 = (ucharT*)alloc((size_t)(n + 1) * 64);      // H2' fp8, +sentinel row
  ushortT* Ab = (ushortT*)alloc((size_t)n * 128 * 2);       // A bf16
  float* dis = (float*)alloc((size_t)n * 4);
  int2* rpc = (int2*)alloc((size_t)n * 8);                  // (row_ptr, count)
  int* gbc = (int*)alloc(512 * 4);
  int* bbase = (int*)alloc(512 * 4);
  int* gcur = (int*)alloc(512 * 4);
  ushortT* Wt1 = (ushortT*)alloc(16384 * 2);
  ushortT* Wt2 = (ushortT*)alloc(8192 * 2);
  int* tmp = (int*)alloc((size_t)E * 4);
  int* col = (int*)alloc(((size_t)E + 4096) * 4);  // slack covers pipeline over-read

  (void)hipMemsetAsync(gbc, 0, 512 * sizeof(int), stream);

  const int gChunks = (E + 8191) / 8192;

  bhist_k<<<gChunks, 256, 0, stream>>>(dstv, E, B, gbc, W1, W2, x, Wt1, Wt2);
  bscan_k<<<1, 256, 0, stream>>>(gbc, B, bbase, gcur);
  bin_k<<<gChunks, 256, 0, stream>>>(srcv, dstv, E, B, gcur, tmp);
  csr_k<<<B, 256, 0, stream>>>(tmp, bbase, gbc, n, rpc, dis, col);

  // grids cover n+1 rows so the sentinel row is written even when n%128==0
  gemm1_k<<<(n + 128) / 128, 512, 0, stream>>>(x, Wt1, dis, Hb8, n);
  agg1_k<<<(n + 15) / 16, 256, 0, stream>>>(Hb8, col, rpc, dis, b1, x, Ab, n);
  gemm2_k<<<(n + 128) / 128, 512, 0, stream>>>(Ab, Wt2, dis, H2b8, n);
  agg2_k<<<(n + 15) / 16, 256, 0, stream>>>(H2b8, col, rpc, dis, b2, x, d_out, n);
}